// Round 14
// baseline (309.913 us; speedup 1.0000x reference)
//
#include <hip/hip_runtime.h>
#include <stdint.h>

typedef unsigned short u16;
typedef u16   u16x4v __attribute__((ext_vector_type(4)));
typedef u16   u16x8v __attribute__((ext_vector_type(8)));
typedef short s16x8v __attribute__((ext_vector_type(8)));
typedef float f32x4v __attribute__((ext_vector_type(4)));

#define DEV static __device__ __forceinline__
#define VOLI(x) (*((volatile int*)&(x)))

// fp32 -> bf16 round-to-nearest-even (scalar)
DEV u16 f2bf(float f){
  union { float f; unsigned u; } v; v.f = f;
  unsigned r = v.u + 0x7FFFu + ((v.u >> 16) & 1u);
  return (u16)(r >> 16);
}

DEV f32x4v mfma16(s16x8v a, s16x8v b, f32x4v c){
  return __builtin_amdgcn_mfma_f32_16x16x32_bf16(a, b, c, 0, 0, 0);
}

// ---------------------------------------------------------------------------
// k_wall: all weight prep in one launch. (unchanged — passed)
__global__ __launch_bounds__(256) void k_wall(const float* __restrict__ w_qs,
                                              const float* __restrict__ w_ks,
                                              const float* __restrict__ w_vs,
                                              const float* __restrict__ proj_w,
                                              u16* __restrict__ wt, u16* __restrict__ wtp,
                                              float qscale){
  int gid = blockIdx.x;
  int tsel = gid >> 10;
  int e = (gid & 1023) * 256 + threadIdx.x;
  if(tsel == 3){
    wtp[e] = f2bf(proj_w[e]);
  } else {
    const float* w = tsel == 0 ? w_qs : (tsel == 1 ? w_ks : w_vs);
    float sc = tsel == 0 ? qscale : 1.0f;
    int n = e >> 9, d = e & 511;
    int h = n >> 6, kk = n & 63;
    wt[tsel * 262144 + n * 512 + d] = f2bf(w[h * 32768 + d * 64 + kk] * sc);
  }
}

// ---------------------------------------------------------------------------
// Fused QKV projection (unchanged — passed).
__global__ __launch_bounds__(256) void k_qkv(const float* __restrict__ Q,
                                             const float* __restrict__ K,
                                             const float* __restrict__ V,
                                             const u16* __restrict__ Wt,
                                             u16* __restrict__ qhh, u16* __restrict__ khh,
                                             u16* __restrict__ vtt){
  __shared__ __align__(16) u16 Xs[32 * 520];
  const int t = threadIdx.x;
  const int lane = t & 63, w = t >> 6;
  const int g = lane >> 4, li = lane & 15;
  const int i0 = blockIdx.x * 32;
  const int y = blockIdx.y;
  const int tsel = y >> 1;
  const float* X = tsel == 0 ? Q : (tsel == 1 ? K : V);
  const int n0 = (y & 1) * 256 + w * 64;

  #pragma unroll
  for(int it = 0; it < 16; ++it){
    int s = it * 256 + t, row = s >> 7, c4 = s & 127;
    f32x4v xv = *(const f32x4v*)(X + (size_t)(i0 + row) * 512 + c4 * 4);
    u16x4v bv; bv[0]=f2bf(xv[0]); bv[1]=f2bf(xv[1]); bv[2]=f2bf(xv[2]); bv[3]=f2bf(xv[3]);
    *(u16x4v*)(Xs + row * 520 + c4 * 4) = bv;
  }
  __syncthreads();

  const int wbase = tsel * 512 + n0;
  const u16* wp0 = Wt + (size_t)(wbase +  0 + li) * 512 + g * 8;
  const u16* wp1 = Wt + (size_t)(wbase + 16 + li) * 512 + g * 8;
  const u16* wp2 = Wt + (size_t)(wbase + 32 + li) * 512 + g * 8;
  const u16* wp3 = Wt + (size_t)(wbase + 48 + li) * 512 + g * 8;

#define LOADW(S, c) { \
  S##0 = *(const s16x8v*)(wp0 + (c) * 32); \
  S##1 = *(const s16x8v*)(wp1 + (c) * 32); \
  S##2 = *(const s16x8v*)(wp2 + (c) * 32); \
  S##3 = *(const s16x8v*)(wp3 + (c) * 32); }
#define COMPW(S, c) { \
  int k0 = (c) * 32 + g * 8; \
  s16x8v a0 = *(const s16x8v*)(Xs + li * 520 + k0); \
  s16x8v a1 = *(const s16x8v*)(Xs + (16 + li) * 520 + k0); \
  acc[0][0] = mfma16(a0, S##0, acc[0][0]); acc[1][0] = mfma16(a1, S##0, acc[1][0]); \
  acc[0][1] = mfma16(a0, S##1, acc[0][1]); acc[1][1] = mfma16(a1, S##1, acc[1][1]); \
  acc[0][2] = mfma16(a0, S##2, acc[0][2]); acc[1][2] = mfma16(a1, S##2, acc[1][2]); \
  acc[0][3] = mfma16(a0, S##3, acc[0][3]); acc[1][3] = mfma16(a1, S##3, acc[1][3]); }

  f32x4v acc[2][4] = {};
  s16x8v wA0, wA1, wA2, wA3, wB0, wB1, wB2, wB3;
  LOADW(wA, 0);
  #pragma unroll
  for(int c = 0; c < 16; c += 2){
    LOADW(wB, c + 1);
    COMPW(wA, c);
    if(c + 2 < 16) LOADW(wA, c + 2);
    COMPW(wB, c + 1);
  }
#undef LOADW
#undef COMPW

  if(tsel < 2){
    u16* Y = tsel == 0 ? qhh : khh;
    #pragma unroll
    for(int rg = 0; rg < 2; ++rg)
      #pragma unroll
      for(int j = 0; j < 4; ++j){
        int n = n0 + j * 16 + li, h = n >> 6, dk = n & 63;
        #pragma unroll
        for(int r = 0; r < 4; ++r){
          int i = i0 + rg * 16 + g * 4 + r, bb = i >> 11, m = i & 2047;
          Y[((size_t)(h * 4 + bb) * 2048 + m) * 64 + dk] = f2bf(acc[rg][j][r]);
        }
      }
  } else {
    #pragma unroll
    for(int rg = 0; rg < 2; ++rg)
      #pragma unroll
      for(int j = 0; j < 4; ++j){
        int n = n0 + j * 16 + li;
        u16x4v pk;
        #pragma unroll
        for(int r = 0; r < 4; ++r) pk[r] = f2bf(acc[rg][j][r]);
        *(u16x4v*)(vtt + (size_t)n * 8192 + i0 + g * 8 + rg * 4) = pk;
      }
  }
}

// ---------------------------------------------------------------------------
// Attention, producer/consumer: 6 waves = 4 compute (2 qs x 2 mh) + 2 storers.
// Compute waves issue ZERO global stores in the hot loop (pure-load vmcnt);
// P tiles go to double-buffered LDS; storer waves drain them as full 128B
// lines with nontemporal stores, absorbing all store-ack latency.

#define LOADK(B, ht) { \
  const u16* _p = kp + (size_t)(ht) * 2048; \
  B##0 = *(const s16x8v*)(_p); \
  B##1 = *(const s16x8v*)(_p + 32); \
  B##2 = *(const s16x8v*)(_p + 1024); \
  B##3 = *(const s16x8v*)(_p + 1056); }

#define STEPA(B) { \
  f32x4v z0 = {}, z1 = {}; \
  z0 = mfma16(B##0, bq00, z0); z0 = mfma16(B##1, bq01, z0); \
  z1 = mfma16(B##2, bq00, z1); z1 = mfma16(B##3, bq01, z1); \
  _Pragma("unroll") for(int r = 0; r < 4; ++r){ s00[r] += exp2f(z0[r]); s01[r] += exp2f(z1[r]); } \
  f32x4v y0 = {}, y1 = {}; \
  y0 = mfma16(B##0, bq10, y0); y0 = mfma16(B##1, bq11, y0); \
  y1 = mfma16(B##2, bq10, y1); y1 = mfma16(B##3, bq11, y1); \
  _Pragma("unroll") for(int r = 0; r < 4; ++r){ s10[r] += exp2f(y0[r]); s11[r] += exp2f(y1[r]); } }

#define LOADV(B, ht) { \
  const u16* _p = vp + (ht) * 32; \
  B##0 = *(const s16x8v*)(_p); \
  B##1 = *(const s16x8v*)(_p + 131072); \
  B##2 = *(const s16x8v*)(_p + 262144); \
  B##3 = *(const s16x8v*)(_p + 393216); }

// compute half: QK -> P -> swizzled LDS tile write + PV MFMA (no global store)
#define QSW(KB, VB, bqa, bqb, lb, qs_, tile) { \
  f32x4v z0 = {}, z1 = {}; \
  z0 = mfma16(KB##0, bqa, z0); z0 = mfma16(KB##1, bqb, z0); \
  z1 = mfma16(KB##2, bqa, z1); z1 = mfma16(KB##3, bqb, z1); \
  f32x4v p0, p1; \
  _Pragma("unroll") for(int r = 0; r < 4; ++r){ p0[r] = exp2f(z0[r] + lb); p1[r] = exp2f(z1[r] + lb); } \
  *(f32x4v*)((tile) + (qs_) * 512 + li * 32 + (((g)     ^ (li & 7)) << 2)) = p0; \
  *(f32x4v*)((tile) + (qs_) * 512 + li * 32 + (((g + 4) ^ (li & 7)) << 2)) = p1; \
  union { u16 hh[8]; s16x8v v; } _u; \
  _Pragma("unroll") for(int r = 0; r < 4; ++r){ _u.hh[r] = f2bf(p0[r]); _u.hh[4 + r] = f2bf(p1[r]); } \
  acc##qs_##0 = mfma16(_u.v, VB##0, acc##qs_##0); \
  acc##qs_##1 = mfma16(_u.v, VB##1, acc##qs_##1); \
  acc##qs_##2 = mfma16(_u.v, VB##2, acc##qs_##2); \
  acc##qs_##3 = mfma16(_u.v, VB##3, acc##qs_##3); }

#define PSTEP(KB, VB, s) { \
  if((s) >= 2){ while(VOLI(ackf[w]) < (s) - 2){ __builtin_amdgcn_s_sleep(1); } } \
  asm volatile("" ::: "memory"); \
  float* tile = &Ptb[w][(s) & 1][0][0]; \
  QSW(KB, VB, bq00, bq01, lb0, 0, tile); \
  QSW(KB, VB, bq10, bq11, lb1, 1, tile); \
  asm volatile("s_waitcnt lgkmcnt(0)" ::: "memory"); \
  if(lane == 0) VOLI(rdyf[w]) = (s); }

__global__ __launch_bounds__(384, 3) void k_attn(const u16* __restrict__ QHH, const u16* __restrict__ KHH,
                                                 const u16* __restrict__ VTT,
                                                 u16* __restrict__ XC, float* __restrict__ ATT){
  __shared__ float Lp[2][2][32];                    // [qs][mh][row]
  __shared__ float AccS[2][32][64];                 // 16 KB
  __shared__ __align__(16) float Ptb[4][2][2][512]; // [cw][buf][qs_][...] 32 KB
  __shared__ int rdyf[4], ackf[4];
  const int t = threadIdx.x, lane = t & 63, w = t >> 6;   // w 0..5
  const int g = lane >> 4, li = lane & 15;
  const int rr = lane >> 3, cc = lane & 7;
  const int qs = w >> 1, mh = w & 1;                 // valid for w<4
  const int gid = blockIdx.x;                        // 0..1023
  const int xcd = gid & 7, rem = gid >> 3;
  const int qt = rem & 31;
  const int hb = xcd * 4 + (rem >> 5);
  const int h = hb >> 2, b = hb & 3;
  const size_t base_hb = (size_t)hb * 2048;
  const int qbase = qt * 64 + qs * 32;

  // init flags before barrier 1
  if(lane == 0){
    if(w < 4) VOLI(rdyf[w]) = -1;
    else { VOLI(ackf[(w - 4) * 2]) = -1; VOLI(ackf[(w - 4) * 2 + 1]) = -1; }
  }

  s16x8v bq00 = {}, bq01 = {}, bq10 = {}, bq11 = {};
  const u16* kp = nullptr; const u16* vp = nullptr;
  if(w < 4){
    const u16* qp0 = QHH + (base_hb + qbase + li) * 64 + g * 8;
    const u16* qp1 = QHH + (base_hb + qbase + 16 + li) * 64 + g * 8;
    bq00 = *(const s16x8v*)(qp0); bq01 = *(const s16x8v*)(qp0 + 32);
    bq10 = *(const s16x8v*)(qp1); bq11 = *(const s16x8v*)(qp1 + 32);
    kp = KHH + (base_hb + li) * 64 + g * 8 + (size_t)mh * 65536;
    vp = VTT + (size_t)(h * 64 + li) * 8192 + b * 2048 + g * 8 + mh * 1024;

    // ---- pass A: per-lane exp2 partial sums over this wave's 1024 keys ----
    f32x4v s00 = {}, s01 = {}, s10 = {}, s11 = {};
    {
      s16x8v kA0, kA1, kA2, kA3, kB0, kB1, kB2, kB3;
      LOADK(kA, 0);
      for(int ht = 0; ht < 30; ht += 2){
        LOADK(kB, ht + 1);
        STEPA(kA);
        LOADK(kA, ht + 2);
        STEPA(kB);
      }
      LOADK(kB, 31);
      STEPA(kA);
      STEPA(kB);
    }
    float l0 = (s00[0]+s00[1]+s00[2]+s00[3]) + (s01[0]+s01[1]+s01[2]+s01[3]);
    float l1 = (s10[0]+s10[1]+s10[2]+s10[3]) + (s11[0]+s11[1]+s11[2]+s11[3]);
    l0 += __shfl_xor(l0, 16, 64); l0 += __shfl_xor(l0, 32, 64);
    l1 += __shfl_xor(l1, 16, 64); l1 += __shfl_xor(l1, 32, 64);
    if(lane < 16){ Lp[qs][mh][li] = l0; Lp[qs][mh][16 + li] = l1; }
  }
  __syncthreads();   // barrier 1 (all 6 waves)

  f32x4v acc00 = {}, acc01 = {}, acc02 = {}, acc03 = {};
  f32x4v acc10 = {}, acc11 = {}, acc12 = {}, acc13 = {};

  if(w < 4){
    const float lb0 = -__log2f(Lp[qs][0][li]      + Lp[qs][1][li]);
    const float lb1 = -__log2f(Lp[qs][0][16 + li] + Lp[qs][1][16 + li]);
    // ---- pass B producer ----
    s16x8v kA0, kA1, kA2, kA3, kB0, kB1, kB2, kB3;
    s16x8v vA0, vA1, vA2, vA3, vB0, vB1, vB2, vB3;
    LOADK(kA, 0); LOADV(vA, 0);
    for(int ht = 0; ht < 30; ht += 2){
      LOADK(kB, ht + 1); LOADV(vB, ht + 1);
      PSTEP(kA, vA, ht);
      LOADK(kA, ht + 2); LOADV(vA, ht + 2);
      PSTEP(kB, vB, ht + 1);
    }
    LOADK(kB, 31); LOADV(vB, 31);
    PSTEP(kA, vA, 30);
    PSTEP(kB, vB, 31);

    if(mh == 1){
      #pragma unroll
      for(int r = 0; r < 4; ++r){
        AccS[qs][ 0 + r][lane] = acc00[r];
        AccS[qs][ 4 + r][lane] = acc01[r];
        AccS[qs][ 8 + r][lane] = acc02[r];
        AccS[qs][12 + r][lane] = acc03[r];
        AccS[qs][16 + r][lane] = acc10[r];
        AccS[qs][20 + r][lane] = acc11[r];
        AccS[qs][24 + r][lane] = acc12[r];
        AccS[qs][28 + r][lane] = acc13[r];
      }
    }
  } else {
    // ---- storer waves: drain P tiles for 2 compute waves ----
    const int cw0 = (w - 4) * 2, cw1 = cw0 + 1;
    for(int s = 0; s < 32; ++s){
      #pragma unroll
      for(int pick = 0; pick < 2; ++pick){
        const int cwv = pick == 0 ? cw0 : cw1;
        while(VOLI(rdyf[cwv]) < s){ __builtin_amdgcn_s_sleep(1); }
        asm volatile("" ::: "memory");
        const float* tp = &Ptb[cwv][s & 1][0][0];
        f32x4v q00 = *(const f32x4v*)(tp + rr * 32 + ((cc ^ rr) << 2));
        f32x4v q01 = *(const f32x4v*)(tp + (8 + rr) * 32 + ((cc ^ rr) << 2));
        f32x4v q10 = *(const f32x4v*)(tp + 512 + rr * 32 + ((cc ^ rr) << 2));
        f32x4v q11 = *(const f32x4v*)(tp + 512 + (8 + rr) * 32 + ((cc ^ rr) << 2));
        asm volatile("s_waitcnt lgkmcnt(0)" ::: "memory");
        if(lane == 0) VOLI(ackf[cwv]) = s;
        float* ab = ATT + (base_hb + qt * 64 + (cwv >> 1) * 32 + rr) * 2048
                        + (cwv & 1) * 1024 + s * 32 + cc * 4;
        __builtin_nontemporal_store(q00, (f32x4v*)(ab));
        __builtin_nontemporal_store(q01, (f32x4v*)(ab + 8 * 2048));
        __builtin_nontemporal_store(q10, (f32x4v*)(ab + 16 * 2048));
        __builtin_nontemporal_store(q11, (f32x4v*)(ab + 24 * 2048));
      }
    }
  }
  __syncthreads();   // barrier 2 (all 6 waves)

  if(w < 4 && mh == 0){
    #pragma unroll
    for(int r = 0; r < 4; ++r){
      acc00[r] += AccS[qs][ 0 + r][lane];
      acc01[r] += AccS[qs][ 4 + r][lane];
      acc02[r] += AccS[qs][ 8 + r][lane];
      acc03[r] += AccS[qs][12 + r][lane];
      acc10[r] += AccS[qs][16 + r][lane];
      acc11[r] += AccS[qs][20 + r][lane];
      acc12[r] += AccS[qs][24 + r][lane];
      acc13[r] += AccS[qs][28 + r][lane];
    }
    #pragma unroll
    for(int r = 0; r < 4; ++r){
      int row0 = qbase + g * 4 + r;
      int row1 = qbase + 16 + g * 4 + r;
      u16* x0 = XC + (size_t)(b * 2048 + row0) * 512 + h * 64 + li;
      u16* x1 = XC + (size_t)(b * 2048 + row1) * 512 + h * 64 + li;
      x0[0]  = f2bf(acc00[r]); x0[16] = f2bf(acc01[r]); x0[32] = f2bf(acc02[r]); x0[48] = f2bf(acc03[r]);
      x1[0]  = f2bf(acc10[r]); x1[16] = f2bf(acc11[r]); x1[32] = f2bf(acc12[r]); x1[48] = f2bf(acc13[r]);
    }
  }
}

// ---------------------------------------------------------------------------
// Out-projection + bias + residual + LayerNorm (unchanged — passed).
__global__ __launch_bounds__(512) void k_out(const u16* __restrict__ Xb,
                                             const u16* __restrict__ Wtp,
                                             float* __restrict__ Yf,
                                             const float* __restrict__ bias,
                                             const float* __restrict__ resid,
                                             const float* __restrict__ a2,
                                             const float* __restrict__ b2){
  __shared__ __align__(16) u16 Xs[16 * 520];
  __shared__ float sred[8][16], sqred[8][16], muL[16], rsL[16];
  const int t = threadIdx.x;
  const int lane = t & 63, w = t >> 6;
  const int g = lane >> 4, li = lane & 15;
  const int i0 = blockIdx.x * 16;
  const int n0 = w * 64;

  #pragma unroll
  for(int it = 0; it < 2; ++it){
    int s = it * 512 + t, row = s >> 6, c8 = s & 63;
    u16x8v xv = *(const u16x8v*)(Xb + (size_t)(i0 + row) * 512 + c8 * 8);
    *(u16x8v*)(Xs + row * 520 + c8 * 8) = xv;
  }
  __syncthreads();

  const u16* wp0 = Wtp + (size_t)(n0 +  0 + li) * 512 + g * 8;
  const u16* wp1 = Wtp + (size_t)(n0 + 16 + li) * 512 + g * 8;
  const u16* wp2 = Wtp + (size_t)(n0 + 32 + li) * 512 + g * 8;
  const u16* wp3 = Wtp + (size_t)(n0 + 48 + li) * 512 + g * 8;

#define LOADW(S, c) { \
  S##0 = *(const s16x8v*)(wp0 + (c) * 32); \
  S##1 = *(const s16x8v*)(wp1 + (c) * 32); \
  S##2 = *(const s16x8v*)(wp2 + (c) * 32); \
  S##3 = *(const s16x8v*)(wp3 + (c) * 32); }
#define COMPW(S, c) { \
  int k0 = (c) * 32 + g * 8; \
  s16x8v a0 = *(const s16x8v*)(Xs + li * 520 + k0); \
  acc[0] = mfma16(a0, S##0, acc[0]); \
  acc[1] = mfma16(a0, S##1, acc[1]); \
  acc[2] = mfma16(a0, S##2, acc[2]); \
  acc[3] = mfma16(a0, S##3, acc[3]); }

  f32x4v acc[4] = {};
  s16x8v wA0, wA1, wA2, wA3, wB0, wB1, wB2, wB3;
  LOADW(wA, 0);
  #pragma unroll
  for(int c = 0; c < 16; c += 2){
    LOADW(wB, c + 1);
    COMPW(wA, c);
    if(c + 2 < 16) LOADW(wA, c + 2);
    COMPW(wB, c + 1);
  }
#undef LOADW
#undef COMPW

  float zres[4][4];
  #pragma unroll
  for(int j = 0; j < 4; ++j){
    int n = n0 + j * 16 + li;
    float bv = bias[n];
    #pragma unroll
    for(int r = 0; r < 4; ++r){
      int i = i0 + g * 4 + r;
      zres[j][r] = acc[j][r] + bv + resid[(size_t)i * 512 + n];
    }
  }
  #pragma unroll
  for(int r = 0; r < 4; ++r){
    float S = 0.f, SQ = 0.f;
    #pragma unroll
    for(int j = 0; j < 4; ++j){ float zz = zres[j][r]; S += zz; SQ += zz * zz; }
    #pragma unroll
    for(int off = 1; off < 16; off <<= 1){ S += __shfl_xor(S, off, 16); SQ += __shfl_xor(SQ, off, 16); }
    if(li == 0){ sred[w][g * 4 + r] = S; sqred[w][g * 4 + r] = SQ; }
  }
  __syncthreads();
  if(t < 16){
    float S = 0.f, SQ = 0.f;
    #pragma unroll
    for(int ww = 0; ww < 8; ++ww){ S += sred[ww][t]; SQ += sqred[ww][t]; }
    float mu = S * (1.0f / 512.0f);
    float var = (SQ - 512.0f * mu * mu) * (1.0f / 511.0f);
    muL[t] = mu;
    rsL[t] = 1.0f / (sqrtf(fmaxf(var, 0.0f)) + 1e-3f);
  }
  __syncthreads();
  #pragma unroll
  for(int r = 0; r < 4; ++r){
    int rloc = g * 4 + r;
    float mu = muL[rloc], rs = rsL[rloc];
    size_t ib = (size_t)(i0 + rloc) * 512;
    #pragma unroll
    for(int j = 0; j < 4; ++j){
      int n = n0 + j * 16 + li;
      Yf[ib + n] = (zres[j][r] - mu) * rs * a2[n] + b2[n];
    }
  }
}

// ---------------------------------------------------------------------------
extern "C" void kernel_launch(void* const* d_in, const int* in_sizes, int n_in,
                              void* d_out, int out_size, void* d_ws, size_t ws_size,
                              hipStream_t stream){
  const float* q      = (const float*)d_in[0];
  const float* k      = (const float*)d_in[1];
  const float* v      = (const float*)d_in[2];
  const float* w_qs   = (const float*)d_in[3];
  const float* w_ks   = (const float*)d_in[4];
  const float* w_vs   = (const float*)d_in[5];
  const float* proj_w = (const float*)d_in[6];
  const float* proj_b = (const float*)d_in[7];
  const float* a2     = (const float*)d_in[8];
  const float* b2     = (const float*)d_in[9];

  char* ws = (char*)d_ws;
  u16* wt    = (u16*)(ws);                       // 3 x 512KB (q-weights pre-scaled)
  u16* wtp   = (u16*)(ws + 1572864);             // 512KB proj_w bf16
  u16* qhh   = (u16*)(ws + 2097152);             // 8 MB head-major
  u16* khh   = (u16*)(ws + 10485760);            // 8 MB head-major
  u16* vtt   = (u16*)(ws + 18874368);            // 8 MB [n][perm(i)]
  u16* xc    = (u16*)(ws + 27262976);             // 8 MB [i][512]

  float* out = (float*)d_out;                    // (4,2048,512) fp32
  float* att = out + 4194304;                    // (32,2048,2048) fp32

  // fold 1/sqrt(512) * log2(e) into the Q projection weights
  const float qscale = 0.06375872032774575f;

  k_wall<<<dim3(4096), 256, 0, stream>>>(w_qs, w_ks, w_vs, proj_w, wt, wtp, qscale);
  k_qkv <<<dim3(256, 6), 256, 0, stream>>>(q, k, v, wt, qhh, khh, vtt);
  k_attn<<<dim3(1024), 384, 0, stream>>>(qhh, khh, vtt, xc, att);
  k_out <<<dim3(512), 512, 0, stream>>>(xc, wtp, out, proj_b, q, a2, b2);
}

// Round 15
// 291.273 us; speedup vs baseline: 1.0640x; 1.0640x over previous
//
#include <hip/hip_runtime.h>
#include <stdint.h>

typedef unsigned short u16;
typedef u16   u16x4v __attribute__((ext_vector_type(4)));
typedef u16   u16x8v __attribute__((ext_vector_type(8)));
typedef short s16x8v __attribute__((ext_vector_type(8)));
typedef float f32x4v __attribute__((ext_vector_type(4)));

#define DEV static __device__ __forceinline__

// fp32 -> bf16 round-to-nearest-even (scalar)
DEV u16 f2bf(float f){
  union { float f; unsigned u; } v; v.f = f;
  unsigned r = v.u + 0x7FFFu + ((v.u >> 16) & 1u);
  return (u16)(r >> 16);
}

DEV f32x4v mfma16(s16x8v a, s16x8v b, f32x4v c){
  return __builtin_amdgcn_mfma_f32_16x16x32_bf16(a, b, c, 0, 0, 0);
}

// ---------------------------------------------------------------------------
// k_wall: weight prep. Head weights go through a padded-LDS 64x64 transpose so
// both the global read (f32x4, kk-contiguous) and the write (u16x4,
// d-contiguous) are coalesced. proj_w is a straight coalesced convert.
// Grid: 192 transpose tiles (3 tensors x 8 h x 8 dblk) + 1024 copy blocks.
__global__ __launch_bounds__(256) void k_wall(const float* __restrict__ w_qs,
                                              const float* __restrict__ w_ks,
                                              const float* __restrict__ w_vs,
                                              const float* __restrict__ proj_w,
                                              u16* __restrict__ wt, u16* __restrict__ wtp,
                                              float qscale){
  const int gid = blockIdx.x, t = threadIdx.x;
  if(gid >= 192){
    int e = (gid - 192) * 256 + t;
    wtp[e] = f2bf(proj_w[e]);
    return;
  }
  __shared__ u16 Ts[64 * 65];
  const int tsel = gid >> 6, rem = gid & 63;
  const int h = rem >> 3, db = rem & 7;
  const float* w = tsel == 0 ? w_qs : (tsel == 1 ? w_ks : w_vs);
  const float sc = tsel == 0 ? qscale : 1.0f;
  // read 64 d-rows x 64 kk (f32x4, coalesced), convert, store transposed-ready
  #pragma unroll
  for(int it = 0; it < 4; ++it){
    int idx = it * 256 + t, dr = idx >> 4, q = idx & 15;
    f32x4v v = *(const f32x4v*)(w + (size_t)h * 32768 + (size_t)(db * 64 + dr) * 64 + q * 4);
    #pragma unroll
    for(int e = 0; e < 4; ++e) Ts[dr * 65 + q * 4 + e] = f2bf(v[e] * sc);
  }
  __syncthreads();
  // write wt[tsel*512 + h*64 + kk][db*64 + d] (u16x4, coalesced)
  #pragma unroll
  for(int it = 0; it < 4; ++it){
    int idx = it * 256 + t, kk = idx >> 4, dq = idx & 15;
    u16x4v o;
    #pragma unroll
    for(int e = 0; e < 4; ++e) o[e] = Ts[(dq * 4 + e) * 65 + kk];
    *(u16x4v*)(wt + (size_t)(tsel * 512 + h * 64 + kk) * 512 + db * 64 + dq * 4) = o;
  }
}

// ---------------------------------------------------------------------------
// Fused QKV projection (unchanged — passed).
__global__ __launch_bounds__(256) void k_qkv(const float* __restrict__ Q,
                                             const float* __restrict__ K,
                                             const float* __restrict__ V,
                                             const u16* __restrict__ Wt,
                                             u16* __restrict__ qhh, u16* __restrict__ khh,
                                             u16* __restrict__ vtt){
  __shared__ __align__(16) u16 Xs[32 * 520];
  const int t = threadIdx.x;
  const int lane = t & 63, w = t >> 6;
  const int g = lane >> 4, li = lane & 15;
  const int i0 = blockIdx.x * 32;
  const int y = blockIdx.y;
  const int tsel = y >> 1;
  const float* X = tsel == 0 ? Q : (tsel == 1 ? K : V);
  const int n0 = (y & 1) * 256 + w * 64;

  #pragma unroll
  for(int it = 0; it < 16; ++it){
    int s = it * 256 + t, row = s >> 7, c4 = s & 127;
    f32x4v xv = *(const f32x4v*)(X + (size_t)(i0 + row) * 512 + c4 * 4);
    u16x4v bv; bv[0]=f2bf(xv[0]); bv[1]=f2bf(xv[1]); bv[2]=f2bf(xv[2]); bv[3]=f2bf(xv[3]);
    *(u16x4v*)(Xs + row * 520 + c4 * 4) = bv;
  }
  __syncthreads();

  const int wbase = tsel * 512 + n0;
  const u16* wp0 = Wt + (size_t)(wbase +  0 + li) * 512 + g * 8;
  const u16* wp1 = Wt + (size_t)(wbase + 16 + li) * 512 + g * 8;
  const u16* wp2 = Wt + (size_t)(wbase + 32 + li) * 512 + g * 8;
  const u16* wp3 = Wt + (size_t)(wbase + 48 + li) * 512 + g * 8;

#define LOADW(S, c) { \
  S##0 = *(const s16x8v*)(wp0 + (c) * 32); \
  S##1 = *(const s16x8v*)(wp1 + (c) * 32); \
  S##2 = *(const s16x8v*)(wp2 + (c) * 32); \
  S##3 = *(const s16x8v*)(wp3 + (c) * 32); }
#define COMPW(S, c) { \
  int k0 = (c) * 32 + g * 8; \
  s16x8v a0 = *(const s16x8v*)(Xs + li * 520 + k0); \
  s16x8v a1 = *(const s16x8v*)(Xs + (16 + li) * 520 + k0); \
  acc[0][0] = mfma16(a0, S##0, acc[0][0]); acc[1][0] = mfma16(a1, S##0, acc[1][0]); \
  acc[0][1] = mfma16(a0, S##1, acc[0][1]); acc[1][1] = mfma16(a1, S##1, acc[1][1]); \
  acc[0][2] = mfma16(a0, S##2, acc[0][2]); acc[1][2] = mfma16(a1, S##2, acc[1][2]); \
  acc[0][3] = mfma16(a0, S##3, acc[0][3]); acc[1][3] = mfma16(a1, S##3, acc[1][3]); }

  f32x4v acc[2][4] = {};
  s16x8v wA0, wA1, wA2, wA3, wB0, wB1, wB2, wB3;
  LOADW(wA, 0);
  #pragma unroll
  for(int c = 0; c < 16; c += 2){
    LOADW(wB, c + 1);
    COMPW(wA, c);
    if(c + 2 < 16) LOADW(wA, c + 2);
    COMPW(wB, c + 1);
  }
#undef LOADW
#undef COMPW

  if(tsel < 2){
    u16* Y = tsel == 0 ? qhh : khh;
    #pragma unroll
    for(int rg = 0; rg < 2; ++rg)
      #pragma unroll
      for(int j = 0; j < 4; ++j){
        int n = n0 + j * 16 + li, h = n >> 6, dk = n & 63;
        #pragma unroll
        for(int r = 0; r < 4; ++r){
          int i = i0 + rg * 16 + g * 4 + r, bb = i >> 11, m = i & 2047;
          Y[((size_t)(h * 4 + bb) * 2048 + m) * 64 + dk] = f2bf(acc[rg][j][r]);
        }
      }
  } else {
    #pragma unroll
    for(int rg = 0; rg < 2; ++rg)
      #pragma unroll
      for(int j = 0; j < 4; ++j){
        int n = n0 + j * 16 + li;
        u16x4v pk;
        #pragma unroll
        for(int r = 0; r < 4; ++r) pk[r] = f2bf(acc[rg][j][r]);
        *(u16x4v*)(vtt + (size_t)n * 8192 + i0 + g * 8 + rg * 4) = pk;
      }
  }
}

// ---------------------------------------------------------------------------
// Attention, m-split (r11 structure == best known). Adds s_setprio(1) around
// the MFMA clusters in pass B (T5): MFMA-entering waves win CU arbitration
// against waves issuing loads/stores.

#define LOADK(B, ht) { \
  const u16* _p = kp + (size_t)(ht) * 2048; \
  B##0 = *(const s16x8v*)(_p); \
  B##1 = *(const s16x8v*)(_p + 32); \
  B##2 = *(const s16x8v*)(_p + 1024); \
  B##3 = *(const s16x8v*)(_p + 1056); }

#define STEPA(B) { \
  f32x4v z0 = {}, z1 = {}; \
  z0 = mfma16(B##0, bq00, z0); z0 = mfma16(B##1, bq01, z0); \
  z1 = mfma16(B##2, bq00, z1); z1 = mfma16(B##3, bq01, z1); \
  _Pragma("unroll") for(int r = 0; r < 4; ++r){ s00[r] += exp2f(z0[r]); s01[r] += exp2f(z1[r]); } \
  f32x4v y0 = {}, y1 = {}; \
  y0 = mfma16(B##0, bq10, y0); y0 = mfma16(B##1, bq11, y0); \
  y1 = mfma16(B##2, bq10, y1); y1 = mfma16(B##3, bq11, y1); \
  _Pragma("unroll") for(int r = 0; r < 4; ++r){ s10[r] += exp2f(y0[r]); s11[r] += exp2f(y1[r]); } }

#define LOADV(B, ht) { \
  const u16* _p = vp + (ht) * 32; \
  B##0 = *(const s16x8v*)(_p); \
  B##1 = *(const s16x8v*)(_p + 131072); \
  B##2 = *(const s16x8v*)(_p + 262144); \
  B##3 = *(const s16x8v*)(_p + 393216); }

// Swizzled quad offset inside the wave tile: row*32 + ((quad ^ (row&7))*4)
#define QS_HALF(KB, VB, bqa, bqb, lb, qs_, ht) { \
  __builtin_amdgcn_s_setprio(1); \
  f32x4v z0 = {}, z1 = {}; \
  z0 = mfma16(KB##0, bqa, z0); z0 = mfma16(KB##1, bqb, z0); \
  z1 = mfma16(KB##2, bqa, z1); z1 = mfma16(KB##3, bqb, z1); \
  __builtin_amdgcn_s_setprio(0); \
  f32x4v p0, p1; \
  _Pragma("unroll") for(int r = 0; r < 4; ++r){ p0[r] = exp2f(z0[r] + lb); p1[r] = exp2f(z1[r] + lb); } \
  *(f32x4v*)(Pt + li * 32 + (((g)     ^ (li & 7)) << 2)) = p0; \
  *(f32x4v*)(Pt + li * 32 + (((g + 4) ^ (li & 7)) << 2)) = p1; \
  f32x4v q0 = *(const f32x4v*)(Pt + rr * 32 + ((cc ^ rr) << 2)); \
  f32x4v q1 = *(const f32x4v*)(Pt + (8 + rr) * 32 + ((cc ^ rr) << 2)); \
  float* _ab = attb + (size_t)((qs_) * 16 + rr) * 2048 + (ht) * 32 + cc * 4; \
  __builtin_nontemporal_store(q0, (f32x4v*)(_ab)); \
  __builtin_nontemporal_store(q1, (f32x4v*)(_ab + 8 * 2048)); \
  union { u16 hh[8]; s16x8v v; } _u; \
  _Pragma("unroll") for(int r = 0; r < 4; ++r){ _u.hh[r] = f2bf(p0[r]); _u.hh[4 + r] = f2bf(p1[r]); } \
  __builtin_amdgcn_s_setprio(1); \
  acc##qs_##0 = mfma16(_u.v, VB##0, acc##qs_##0); \
  acc##qs_##1 = mfma16(_u.v, VB##1, acc##qs_##1); \
  acc##qs_##2 = mfma16(_u.v, VB##2, acc##qs_##2); \
  acc##qs_##3 = mfma16(_u.v, VB##3, acc##qs_##3); \
  __builtin_amdgcn_s_setprio(0); }

#define STEPB(KB, VB, ht) { \
  QS_HALF(KB, VB, bq00, bq01, lb0, 0, ht); \
  QS_HALF(KB, VB, bq10, bq11, lb1, 1, ht); }

__global__ __launch_bounds__(256, 3) void k_attn(const u16* __restrict__ QHH, const u16* __restrict__ KHH,
                                                 const u16* __restrict__ VTT,
                                                 u16* __restrict__ XC, float* __restrict__ ATT){
  __shared__ float Lp[2][2][32];        // [qs][mh][row]
  __shared__ float AccS[2][32][64];     // [qs][elem][lane]  = 16 KB
  __shared__ __align__(16) float Pt4[4][512];  // per-wave P transpose tile, 8 KB
  const int t = threadIdx.x, lane = t & 63, w = t >> 6;
  const int g = lane >> 4, li = lane & 15;
  const int rr = lane >> 3, cc = lane & 7;     // store-side row/col-quad
  const int qs = w >> 1, mh = w & 1;
  float* Pt = Pt4[w];
  // XCD swizzle: 32 q-tiles of one hb on one XCD; 4 hb per XCD
  const int gid = blockIdx.x;                // 0..1023
  const int xcd = gid & 7, rem = gid >> 3;   // rem 0..127
  const int qt = rem & 31;
  const int hb = xcd * 4 + (rem >> 5);
  const int h = hb >> 2, b = hb & 3;
  const size_t base_hb = (size_t)hb * 2048;
  const int qbase = qt * 64 + qs * 32;

  s16x8v bq00, bq01, bq10, bq11;
  {
    const u16* qp0 = QHH + (base_hb + qbase + li) * 64 + g * 8;
    const u16* qp1 = QHH + (base_hb + qbase + 16 + li) * 64 + g * 8;
    bq00 = *(const s16x8v*)(qp0); bq01 = *(const s16x8v*)(qp0 + 32);
    bq10 = *(const s16x8v*)(qp1); bq11 = *(const s16x8v*)(qp1 + 32);
  }
  // wave-local K/V/ATT bases include the m-half offset (32 ht-steps each)
  const u16* kp = KHH + (base_hb + li) * 64 + g * 8 + (size_t)mh * 65536;
  const u16* vp = VTT + (size_t)(h * 64 + li) * 8192 + b * 2048 + g * 8 + mh * 1024;
  float* attb = ATT + (base_hb + qbase) * 2048 + mh * 1024;

  // ---- pass A: per-lane exp2 partial sums over this wave's 1024 keys ----
  f32x4v s00 = {}, s01 = {}, s10 = {}, s11 = {};
  {
    s16x8v kA0, kA1, kA2, kA3, kB0, kB1, kB2, kB3;
    LOADK(kA, 0);
    for(int ht = 0; ht < 30; ht += 2){
      LOADK(kB, ht + 1);
      STEPA(kA);
      LOADK(kA, ht + 2);
      STEPA(kB);
    }
    LOADK(kB, 31);
    STEPA(kA);
    STEPA(kB);
  }
  float l0 = (s00[0]+s00[1]+s00[2]+s00[3]) + (s01[0]+s01[1]+s01[2]+s01[3]);
  float l1 = (s10[0]+s10[1]+s10[2]+s10[3]) + (s11[0]+s11[1]+s11[2]+s11[3]);
  l0 += __shfl_xor(l0, 16, 64); l0 += __shfl_xor(l0, 32, 64);
  l1 += __shfl_xor(l1, 16, 64); l1 += __shfl_xor(l1, 32, 64);
  if(lane < 16){ Lp[qs][mh][li] = l0; Lp[qs][mh][16 + li] = l1; }
  __syncthreads();
  // P = exp2(z - log2(l_total)) ; fold normalization into the exponent
  const float lb0 = -__log2f(Lp[qs][0][li]      + Lp[qs][1][li]);
  const float lb1 = -__log2f(Lp[qs][0][16 + li] + Lp[qs][1][16 + li]);

  // ---- pass B over this wave's 1024 keys ----
  f32x4v acc00 = {}, acc01 = {}, acc02 = {}, acc03 = {};
  f32x4v acc10 = {}, acc11 = {}, acc12 = {}, acc13 = {};
  {
    s16x8v kA0, kA1, kA2, kA3, kB0, kB1, kB2, kB3;
    s16x8v vA0, vA1, vA2, vA3, vB0, vB1, vB2, vB3;
    LOADK(kA, 0); LOADV(vA, 0);
    for(int ht = 0; ht < 30; ht += 2){
      LOADK(kB, ht + 1); LOADV(vB, ht + 1);
      STEPB(kA, vA, ht);
      LOADK(kA, ht + 2); LOADV(vA, ht + 2);
      STEPB(kB, vB, ht + 1);
    }
    LOADK(kB, 31); LOADV(vB, 31);
    STEPB(kA, vA, 30);
    STEPB(kB, vB, 31);
  }

  // ---- combine PV partials across m-halves ----
  if(mh == 1){
    #pragma unroll
    for(int r = 0; r < 4; ++r){
      AccS[qs][ 0 + r][lane] = acc00[r];
      AccS[qs][ 4 + r][lane] = acc01[r];
      AccS[qs][ 8 + r][lane] = acc02[r];
      AccS[qs][12 + r][lane] = acc03[r];
      AccS[qs][16 + r][lane] = acc10[r];
      AccS[qs][20 + r][lane] = acc11[r];
      AccS[qs][24 + r][lane] = acc12[r];
      AccS[qs][28 + r][lane] = acc13[r];
    }
  }
  __syncthreads();
  if(mh == 0){
    #pragma unroll
    for(int r = 0; r < 4; ++r){
      acc00[r] += AccS[qs][ 0 + r][lane];
      acc01[r] += AccS[qs][ 4 + r][lane];
      acc02[r] += AccS[qs][ 8 + r][lane];
      acc03[r] += AccS[qs][12 + r][lane];
      acc10[r] += AccS[qs][16 + r][lane];
      acc11[r] += AccS[qs][20 + r][lane];
      acc12[r] += AccS[qs][24 + r][lane];
      acc13[r] += AccS[qs][28 + r][lane];
    }
    #pragma unroll
    for(int r = 0; r < 4; ++r){
      int row0 = qbase + g * 4 + r;
      int row1 = qbase + 16 + g * 4 + r;
      u16* x0 = XC + (size_t)(b * 2048 + row0) * 512 + h * 64 + li;
      u16* x1 = XC + (size_t)(b * 2048 + row1) * 512 + h * 64 + li;
      x0[0]  = f2bf(acc00[r]); x0[16] = f2bf(acc01[r]); x0[32] = f2bf(acc02[r]); x0[48] = f2bf(acc03[r]);
      x1[0]  = f2bf(acc10[r]); x1[16] = f2bf(acc11[r]); x1[32] = f2bf(acc12[r]); x1[48] = f2bf(acc13[r]);
    }
  }
}

// ---------------------------------------------------------------------------
// Out-projection + bias + residual + LayerNorm (unchanged — passed).
__global__ __launch_bounds__(512) void k_out(const u16* __restrict__ Xb,
                                             const u16* __restrict__ Wtp,
                                             float* __restrict__ Yf,
                                             const float* __restrict__ bias,
                                             const float* __restrict__ resid,
                                             const float* __restrict__ a2,
                                             const float* __restrict__ b2){
  __shared__ __align__(16) u16 Xs[16 * 520];
  __shared__ float sred[8][16], sqred[8][16], muL[16], rsL[16];
  const int t = threadIdx.x;
  const int lane = t & 63, w = t >> 6;
  const int g = lane >> 4, li = lane & 15;
  const int i0 = blockIdx.x * 16;
  const int n0 = w * 64;

  #pragma unroll
  for(int it = 0; it < 2; ++it){
    int s = it * 512 + t, row = s >> 6, c8 = s & 63;
    u16x8v xv = *(const u16x8v*)(Xb + (size_t)(i0 + row) * 512 + c8 * 8);
    *(u16x8v*)(Xs + row * 520 + c8 * 8) = xv;
  }
  __syncthreads();

  const u16* wp0 = Wtp + (size_t)(n0 +  0 + li) * 512 + g * 8;
  const u16* wp1 = Wtp + (size_t)(n0 + 16 + li) * 512 + g * 8;
  const u16* wp2 = Wtp + (size_t)(n0 + 32 + li) * 512 + g * 8;
  const u16* wp3 = Wtp + (size_t)(n0 + 48 + li) * 512 + g * 8;

#define LOADW(S, c) { \
  S##0 = *(const s16x8v*)(wp0 + (c) * 32); \
  S##1 = *(const s16x8v*)(wp1 + (c) * 32); \
  S##2 = *(const s16x8v*)(wp2 + (c) * 32); \
  S##3 = *(const s16x8v*)(wp3 + (c) * 32); }
#define COMPW(S, c) { \
  int k0 = (c) * 32 + g * 8; \
  s16x8v a0 = *(const s16x8v*)(Xs + li * 520 + k0); \
  acc[0] = mfma16(a0, S##0, acc[0]); \
  acc[1] = mfma16(a0, S##1, acc[1]); \
  acc[2] = mfma16(a0, S##2, acc[2]); \
  acc[3] = mfma16(a0, S##3, acc[3]); }

  f32x4v acc[4] = {};
  s16x8v wA0, wA1, wA2, wA3, wB0, wB1, wB2, wB3;
  LOADW(wA, 0);
  #pragma unroll
  for(int c = 0; c < 16; c += 2){
    LOADW(wB, c + 1);
    COMPW(wA, c);
    if(c + 2 < 16) LOADW(wA, c + 2);
    COMPW(wB, c + 1);
  }
#undef LOADW
#undef COMPW

  float zres[4][4];
  #pragma unroll
  for(int j = 0; j < 4; ++j){
    int n = n0 + j * 16 + li;
    float bv = bias[n];
    #pragma unroll
    for(int r = 0; r < 4; ++r){
      int i = i0 + g * 4 + r;
      zres[j][r] = acc[j][r] + bv + resid[(size_t)i * 512 + n];
    }
  }
  #pragma unroll
  for(int r = 0; r < 4; ++r){
    float S = 0.f, SQ = 0.f;
    #pragma unroll
    for(int j = 0; j < 4; ++j){ float zz = zres[j][r]; S += zz; SQ += zz * zz; }
    #pragma unroll
    for(int off = 1; off < 16; off <<= 1){ S += __shfl_xor(S, off, 16); SQ += __shfl_xor(SQ, off, 16); }
    if(li == 0){ sred[w][g * 4 + r] = S; sqred[w][g * 4 + r] = SQ; }
  }
  __syncthreads();
  if(t < 16){
    float S = 0.f, SQ = 0.f;
    #pragma unroll
    for(int ww = 0; ww < 8; ++ww){ S += sred[ww][t]; SQ += sqred[ww][t]; }
    float mu = S * (1.0f / 512.0f);
    float var = (SQ - 512.0f * mu * mu) * (1.0f / 511.0f);
    muL[t] = mu;
    rsL[t] = 1.0f / (sqrtf(fmaxf(var, 0.0f)) + 1e-3f);
  }
  __syncthreads();
  #pragma unroll
  for(int r = 0; r < 4; ++r){
    int rloc = g * 4 + r;
    float mu = muL[rloc], rs = rsL[rloc];
    size_t ib = (size_t)(i0 + rloc) * 512;
    #pragma unroll
    for(int j = 0; j < 4; ++j){
      int n = n0 + j * 16 + li;
      Yf[ib + n] = (zres[j][r] - mu) * rs * a2[n] + b2[n];
    }
  }
}

// ---------------------------------------------------------------------------
extern "C" void kernel_launch(void* const* d_in, const int* in_sizes, int n_in,
                              void* d_out, int out_size, void* d_ws, size_t ws_size,
                              hipStream_t stream){
  const float* q      = (const float*)d_in[0];
  const float* k      = (const float*)d_in[1];
  const float* v      = (const float*)d_in[2];
  const float* w_qs   = (const float*)d_in[3];
  const float* w_ks   = (const float*)d_in[4];
  const float* w_vs   = (const float*)d_in[5];
  const float* proj_w = (const float*)d_in[6];
  const float* proj_b = (const float*)d_in[7];
  const float* a2     = (const float*)d_in[8];
  const float* b2     = (const float*)d_in[9];

  char* ws = (char*)d_ws;
  u16* wt    = (u16*)(ws);                       // 3 x 512KB (q-weights pre-scaled)
  u16* wtp   = (u16*)(ws + 1572864);             // 512KB proj_w bf16
  u16* qhh   = (u16*)(ws + 2097152);             // 8 MB head-major
  u16* khh   = (u16*)(ws + 10485760);            // 8 MB head-major
  u16* vtt   = (u16*)(ws + 18874368);            // 8 MB [n][perm(i)]
  u16* xc    = (u16*)(ws + 27262976);            // 8 MB [i][512]

  float* out = (float*)d_out;                    // (4,2048,512) fp32
  float* att = out + 4194304;                    // (32,2048,2048) fp32

  // fold 1/sqrt(512) * log2(e) into the Q projection weights
  const float qscale = 0.06375872032774575f;

  k_wall<<<dim3(1216), 256, 0, stream>>>(w_qs, w_ks, w_vs, proj_w, wt, wtp, qscale);
  k_qkv <<<dim3(256, 6), 256, 0, stream>>>(q, k, v, wt, qhh, khh, vtt);
  k_attn<<<dim3(1024), 256, 0, stream>>>(qhh, khh, vtt, xc, att);
  k_out <<<dim3(512), 512, 0, stream>>>(xc, wtp, out, proj_b, q, a2, b2);
}

// Round 16
// 289.673 us; speedup vs baseline: 1.0699x; 1.0055x over previous
//
#include <hip/hip_runtime.h>
#include <stdint.h>

typedef unsigned short u16;
typedef u16   u16x4v __attribute__((ext_vector_type(4)));
typedef u16   u16x8v __attribute__((ext_vector_type(8)));
typedef short s16x8v __attribute__((ext_vector_type(8)));
typedef float f32x4v __attribute__((ext_vector_type(4)));

#define DEV static __device__ __forceinline__

// fp32 -> bf16 round-to-nearest-even (scalar)
DEV u16 f2bf(float f){
  union { float f; unsigned u; } v; v.f = f;
  unsigned r = v.u + 0x7FFFu + ((v.u >> 16) & 1u);
  return (u16)(r >> 16);
}

DEV f32x4v mfma16(s16x8v a, s16x8v b, f32x4v c){
  return __builtin_amdgcn_mfma_f32_16x16x32_bf16(a, b, c, 0, 0, 0);
}

// ---------------------------------------------------------------------------
// k_wall: weight prep (r15 version — coalesced transpose via padded LDS).
__global__ __launch_bounds__(256) void k_wall(const float* __restrict__ w_qs,
                                              const float* __restrict__ w_ks,
                                              const float* __restrict__ w_vs,
                                              const float* __restrict__ proj_w,
                                              u16* __restrict__ wt, u16* __restrict__ wtp,
                                              float qscale){
  const int gid = blockIdx.x, t = threadIdx.x;
  if(gid >= 192){
    int e = (gid - 192) * 256 + t;
    wtp[e] = f2bf(proj_w[e]);
    return;
  }
  __shared__ u16 Ts[64 * 65];
  const int tsel = gid >> 6, rem = gid & 63;
  const int h = rem >> 3, db = rem & 7;
  const float* w = tsel == 0 ? w_qs : (tsel == 1 ? w_ks : w_vs);
  const float sc = tsel == 0 ? qscale : 1.0f;
  #pragma unroll
  for(int it = 0; it < 4; ++it){
    int idx = it * 256 + t, dr = idx >> 4, q = idx & 15;
    f32x4v v = *(const f32x4v*)(w + (size_t)h * 32768 + (size_t)(db * 64 + dr) * 64 + q * 4);
    #pragma unroll
    for(int e = 0; e < 4; ++e) Ts[dr * 65 + q * 4 + e] = f2bf(v[e] * sc);
  }
  __syncthreads();
  #pragma unroll
  for(int it = 0; it < 4; ++it){
    int idx = it * 256 + t, kk = idx >> 4, dq = idx & 15;
    u16x4v o;
    #pragma unroll
    for(int e = 0; e < 4; ++e) o[e] = Ts[(dq * 4 + e) * 65 + kk];
    *(u16x4v*)(wt + (size_t)(tsel * 512 + h * 64 + kk) * 512 + db * 64 + dq * 4) = o;
  }
}

// ---------------------------------------------------------------------------
// Fused QKV projection (unchanged — passed).
__global__ __launch_bounds__(256) void k_qkv(const float* __restrict__ Q,
                                             const float* __restrict__ K,
                                             const float* __restrict__ V,
                                             const u16* __restrict__ Wt,
                                             u16* __restrict__ qhh, u16* __restrict__ khh,
                                             u16* __restrict__ vtt){
  __shared__ __align__(16) u16 Xs[32 * 520];
  const int t = threadIdx.x;
  const int lane = t & 63, w = t >> 6;
  const int g = lane >> 4, li = lane & 15;
  const int i0 = blockIdx.x * 32;
  const int y = blockIdx.y;
  const int tsel = y >> 1;
  const float* X = tsel == 0 ? Q : (tsel == 1 ? K : V);
  const int n0 = (y & 1) * 256 + w * 64;

  #pragma unroll
  for(int it = 0; it < 16; ++it){
    int s = it * 256 + t, row = s >> 7, c4 = s & 127;
    f32x4v xv = *(const f32x4v*)(X + (size_t)(i0 + row) * 512 + c4 * 4);
    u16x4v bv; bv[0]=f2bf(xv[0]); bv[1]=f2bf(xv[1]); bv[2]=f2bf(xv[2]); bv[3]=f2bf(xv[3]);
    *(u16x4v*)(Xs + row * 520 + c4 * 4) = bv;
  }
  __syncthreads();

  const int wbase = tsel * 512 + n0;
  const u16* wp0 = Wt + (size_t)(wbase +  0 + li) * 512 + g * 8;
  const u16* wp1 = Wt + (size_t)(wbase + 16 + li) * 512 + g * 8;
  const u16* wp2 = Wt + (size_t)(wbase + 32 + li) * 512 + g * 8;
  const u16* wp3 = Wt + (size_t)(wbase + 48 + li) * 512 + g * 8;

#define LOADW(S, c) { \
  S##0 = *(const s16x8v*)(wp0 + (c) * 32); \
  S##1 = *(const s16x8v*)(wp1 + (c) * 32); \
  S##2 = *(const s16x8v*)(wp2 + (c) * 32); \
  S##3 = *(const s16x8v*)(wp3 + (c) * 32); }
#define COMPW(S, c) { \
  int k0 = (c) * 32 + g * 8; \
  s16x8v a0 = *(const s16x8v*)(Xs + li * 520 + k0); \
  s16x8v a1 = *(const s16x8v*)(Xs + (16 + li) * 520 + k0); \
  acc[0][0] = mfma16(a0, S##0, acc[0][0]); acc[1][0] = mfma16(a1, S##0, acc[1][0]); \
  acc[0][1] = mfma16(a0, S##1, acc[0][1]); acc[1][1] = mfma16(a1, S##1, acc[1][1]); \
  acc[0][2] = mfma16(a0, S##2, acc[0][2]); acc[1][2] = mfma16(a1, S##2, acc[1][2]); \
  acc[0][3] = mfma16(a0, S##3, acc[0][3]); acc[1][3] = mfma16(a1, S##3, acc[1][3]); }

  f32x4v acc[2][4] = {};
  s16x8v wA0, wA1, wA2, wA3, wB0, wB1, wB2, wB3;
  LOADW(wA, 0);
  #pragma unroll
  for(int c = 0; c < 16; c += 2){
    LOADW(wB, c + 1);
    COMPW(wA, c);
    if(c + 2 < 16) LOADW(wA, c + 2);
    COMPW(wB, c + 1);
  }
#undef LOADW
#undef COMPW

  if(tsel < 2){
    u16* Y = tsel == 0 ? qhh : khh;
    #pragma unroll
    for(int rg = 0; rg < 2; ++rg)
      #pragma unroll
      for(int j = 0; j < 4; ++j){
        int n = n0 + j * 16 + li, h = n >> 6, dk = n & 63;
        #pragma unroll
        for(int r = 0; r < 4; ++r){
          int i = i0 + rg * 16 + g * 4 + r, bb = i >> 11, m = i & 2047;
          Y[((size_t)(h * 4 + bb) * 2048 + m) * 64 + dk] = f2bf(acc[rg][j][r]);
        }
      }
  } else {
    #pragma unroll
    for(int rg = 0; rg < 2; ++rg)
      #pragma unroll
      for(int j = 0; j < 4; ++j){
        int n = n0 + j * 16 + li;
        u16x4v pk;
        #pragma unroll
        for(int r = 0; r < 4; ++r) pk[r] = f2bf(acc[rg][j][r]);
        *(u16x4v*)(vtt + (size_t)n * 8192 + i0 + g * 8 + rg * 4) = pk;
      }
  }
}

// ---------------------------------------------------------------------------
// Attention, m-split (r11 structure). Pass B now batches TWO ht-steps per
// store sweep: per-wave 16x64 fp32 LDS tile per qs; stores are 4 rows x 256B
// contiguous per instruction (2 full lines/row — halves DRAM page touches).

#define LOADK(B, ht) { \
  const u16* _p = kp + (size_t)(ht) * 2048; \
  B##0 = *(const s16x8v*)(_p); \
  B##1 = *(const s16x8v*)(_p + 32); \
  B##2 = *(const s16x8v*)(_p + 1024); \
  B##3 = *(const s16x8v*)(_p + 1056); }

#define STEPA(B) { \
  f32x4v z0 = {}, z1 = {}; \
  z0 = mfma16(B##0, bq00, z0); z0 = mfma16(B##1, bq01, z0); \
  z1 = mfma16(B##2, bq00, z1); z1 = mfma16(B##3, bq01, z1); \
  _Pragma("unroll") for(int r = 0; r < 4; ++r){ s00[r] += exp2f(z0[r]); s01[r] += exp2f(z1[r]); } \
  f32x4v y0 = {}, y1 = {}; \
  y0 = mfma16(B##0, bq10, y0); y0 = mfma16(B##1, bq11, y0); \
  y1 = mfma16(B##2, bq10, y1); y1 = mfma16(B##3, bq11, y1); \
  _Pragma("unroll") for(int r = 0; r < 4; ++r){ s10[r] += exp2f(y0[r]); s11[r] += exp2f(y1[r]); } }

#define LOADV(B, ht) { \
  const u16* _p = vp + (ht) * 32; \
  B##0 = *(const s16x8v*)(_p); \
  B##1 = *(const s16x8v*)(_p + 131072); \
  B##2 = *(const s16x8v*)(_p + 262144); \
  B##3 = *(const s16x8v*)(_p + 393216); }

// compute one step-half into the pair tile; ph = step parity (col-half).
// tile quad (unswizzled) = ph*8 + {g, g+4}; swizzle: low3 ^= (li & 7).
#define QSW2(KB, VB, bqa, bqb, lb, qs_, ph) { \
  __builtin_amdgcn_s_setprio(1); \
  f32x4v z0 = {}, z1 = {}; \
  z0 = mfma16(KB##0, bqa, z0); z0 = mfma16(KB##1, bqb, z0); \
  z1 = mfma16(KB##2, bqa, z1); z1 = mfma16(KB##3, bqb, z1); \
  __builtin_amdgcn_s_setprio(0); \
  f32x4v p0, p1; \
  _Pragma("unroll") for(int r = 0; r < 4; ++r){ p0[r] = exp2f(z0[r] + lb); p1[r] = exp2f(z1[r] + lb); } \
  float* _tp = &Ptw[w][qs_][0]; \
  *(f32x4v*)(_tp + li * 64 + (((ph) * 8 + ((g)     ^ (li & 7))) << 2)) = p0; \
  *(f32x4v*)(_tp + li * 64 + (((ph) * 8 + ((g + 4) ^ (li & 7))) << 2)) = p1; \
  union { u16 hh[8]; s16x8v v; } _u; \
  _Pragma("unroll") for(int r = 0; r < 4; ++r){ _u.hh[r] = f2bf(p0[r]); _u.hh[4 + r] = f2bf(p1[r]); } \
  __builtin_amdgcn_s_setprio(1); \
  acc##qs_##0 = mfma16(_u.v, VB##0, acc##qs_##0); \
  acc##qs_##1 = mfma16(_u.v, VB##1, acc##qs_##1); \
  acc##qs_##2 = mfma16(_u.v, VB##2, acc##qs_##2); \
  acc##qs_##3 = mfma16(_u.v, VB##3, acc##qs_##3); \
  __builtin_amdgcn_s_setprio(0); }

// store sweep for one qs over the 16x64 pair tile: 4 instrs, each 4 rows x
// 256B contiguous. rr2 = lane>>4 (row within group), cc2 = lane&15 (quad).
#define SST2(qs_, htp) { \
  const float* _tp = &Ptw[w][qs_][0]; \
  _Pragma("unroll") for(int rb = 0; rb < 4; ++rb){ \
    int _row = rb * 4 + rr2; \
    int _ph = cc2 >> 3, _lq = cc2 & 7; \
    f32x4v qv = *(const f32x4v*)(_tp + _row * 64 + ((_ph * 8 + (_lq ^ (_row & 7))) << 2)); \
    float* _ab = attb + (size_t)((qs_) * 16 + _row) * 2048 + (htp) * 32 + cc2 * 4; \
    __builtin_nontemporal_store(qv, (f32x4v*)(_ab)); \
  } }

#define CPAIR(KB, VB, ph) { \
  QSW2(KB, VB, bq00, bq01, lb0, 0, ph); \
  QSW2(KB, VB, bq10, bq11, lb1, 1, ph); }

__global__ __launch_bounds__(256, 3) void k_attn(const u16* __restrict__ QHH, const u16* __restrict__ KHH,
                                                 const u16* __restrict__ VTT,
                                                 u16* __restrict__ XC, float* __restrict__ ATT){
  __shared__ float Lp[2][2][32];            // [qs][mh][row]
  __shared__ float AccS[2][32][64];         // 16 KB
  __shared__ __align__(16) float Ptw[4][2][1024];  // per-wave pair tiles, 32 KB
  const int t = threadIdx.x, lane = t & 63, w = t >> 6;
  const int g = lane >> 4, li = lane & 15;
  const int rr2 = lane >> 4, cc2 = lane & 15;     // store-side row/quad
  const int qs = w >> 1, mh = w & 1;
  // XCD swizzle: 32 q-tiles of one hb on one XCD; 4 hb per XCD
  const int gid = blockIdx.x;                // 0..1023
  const int xcd = gid & 7, rem = gid >> 3;   // rem 0..127
  const int qt = rem & 31;
  const int hb = xcd * 4 + (rem >> 5);
  const int h = hb >> 2, b = hb & 3;
  const size_t base_hb = (size_t)hb * 2048;
  const int qbase = qt * 64 + qs * 32;

  s16x8v bq00, bq01, bq10, bq11;
  {
    const u16* qp0 = QHH + (base_hb + qbase + li) * 64 + g * 8;
    const u16* qp1 = QHH + (base_hb + qbase + 16 + li) * 64 + g * 8;
    bq00 = *(const s16x8v*)(qp0); bq01 = *(const s16x8v*)(qp0 + 32);
    bq10 = *(const s16x8v*)(qp1); bq11 = *(const s16x8v*)(qp1 + 32);
  }
  // wave-local K/V/ATT bases include the m-half offset (32 ht-steps each)
  const u16* kp = KHH + (base_hb + li) * 64 + g * 8 + (size_t)mh * 65536;
  const u16* vp = VTT + (size_t)(h * 64 + li) * 8192 + b * 2048 + g * 8 + mh * 1024;
  float* attb = ATT + (base_hb + qbase) * 2048 + mh * 1024;

  // ---- pass A: per-lane exp2 partial sums over this wave's 1024 keys ----
  f32x4v s00 = {}, s01 = {}, s10 = {}, s11 = {};
  {
    s16x8v kA0, kA1, kA2, kA3, kB0, kB1, kB2, kB3;
    LOADK(kA, 0);
    for(int ht = 0; ht < 30; ht += 2){
      LOADK(kB, ht + 1);
      STEPA(kA);
      LOADK(kA, ht + 2);
      STEPA(kB);
    }
    LOADK(kB, 31);
    STEPA(kA);
    STEPA(kB);
  }
  float l0 = (s00[0]+s00[1]+s00[2]+s00[3]) + (s01[0]+s01[1]+s01[2]+s01[3]);
  float l1 = (s10[0]+s10[1]+s10[2]+s10[3]) + (s11[0]+s11[1]+s11[2]+s11[3]);
  l0 += __shfl_xor(l0, 16, 64); l0 += __shfl_xor(l0, 32, 64);
  l1 += __shfl_xor(l1, 16, 64); l1 += __shfl_xor(l1, 32, 64);
  if(lane < 16){ Lp[qs][mh][li] = l0; Lp[qs][mh][16 + li] = l1; }
  __syncthreads();
  // P = exp2(z - log2(l_total)) ; fold normalization into the exponent
  const float lb0 = -__log2f(Lp[qs][0][li]      + Lp[qs][1][li]);
  const float lb1 = -__log2f(Lp[qs][0][16 + li] + Lp[qs][1][16 + li]);

  // ---- pass B over this wave's 1024 keys, 2-step store batching ----
  f32x4v acc00 = {}, acc01 = {}, acc02 = {}, acc03 = {};
  f32x4v acc10 = {}, acc11 = {}, acc12 = {}, acc13 = {};
  {
    s16x8v kA0, kA1, kA2, kA3, kB0, kB1, kB2, kB3;
    s16x8v vA0, vA1, vA2, vA3, vB0, vB1, vB2, vB3;
    LOADK(kA, 0); LOADV(vA, 0);
    for(int ht = 0; ht < 30; ht += 2){
      LOADK(kB, ht + 1); LOADV(vB, ht + 1);
      CPAIR(kA, vA, 0);                        // step ht -> col-half 0
      LOADK(kA, ht + 2); LOADV(vA, ht + 2);
      CPAIR(kB, vB, 1);                        // step ht+1 -> col-half 1
      SST2(0, ht); SST2(1, ht);                // 256B-contiguous stores
    }
    LOADK(kB, 31); LOADV(vB, 31);
    CPAIR(kA, vA, 0);
    CPAIR(kB, vB, 1);
    SST2(0, 30); SST2(1, 30);
  }

  // ---- combine PV partials across m-halves ----
  if(mh == 1){
    #pragma unroll
    for(int r = 0; r < 4; ++r){
      AccS[qs][ 0 + r][lane] = acc00[r];
      AccS[qs][ 4 + r][lane] = acc01[r];
      AccS[qs][ 8 + r][lane] = acc02[r];
      AccS[qs][12 + r][lane] = acc03[r];
      AccS[qs][16 + r][lane] = acc10[r];
      AccS[qs][20 + r][lane] = acc11[r];
      AccS[qs][24 + r][lane] = acc12[r];
      AccS[qs][28 + r][lane] = acc13[r];
    }
  }
  __syncthreads();
  if(mh == 0){
    #pragma unroll
    for(int r = 0; r < 4; ++r){
      acc00[r] += AccS[qs][ 0 + r][lane];
      acc01[r] += AccS[qs][ 4 + r][lane];
      acc02[r] += AccS[qs][ 8 + r][lane];
      acc03[r] += AccS[qs][12 + r][lane];
      acc10[r] += AccS[qs][16 + r][lane];
      acc11[r] += AccS[qs][20 + r][lane];
      acc12[r] += AccS[qs][24 + r][lane];
      acc13[r] += AccS[qs][28 + r][lane];
    }
    #pragma unroll
    for(int r = 0; r < 4; ++r){
      int row0 = qbase + g * 4 + r;
      int row1 = qbase + 16 + g * 4 + r;
      u16* x0 = XC + (size_t)(b * 2048 + row0) * 512 + h * 64 + li;
      u16* x1 = XC + (size_t)(b * 2048 + row1) * 512 + h * 64 + li;
      x0[0]  = f2bf(acc00[r]); x0[16] = f2bf(acc01[r]); x0[32] = f2bf(acc02[r]); x0[48] = f2bf(acc03[r]);
      x1[0]  = f2bf(acc10[r]); x1[16] = f2bf(acc11[r]); x1[32] = f2bf(acc12[r]); x1[48] = f2bf(acc13[r]);
    }
  }
}

// ---------------------------------------------------------------------------
// Out-projection + bias + residual + LayerNorm (unchanged — passed).
__global__ __launch_bounds__(512) void k_out(const u16* __restrict__ Xb,
                                             const u16* __restrict__ Wtp,
                                             float* __restrict__ Yf,
                                             const float* __restrict__ bias,
                                             const float* __restrict__ resid,
                                             const float* __restrict__ a2,
                                             const float* __restrict__ b2){
  __shared__ __align__(16) u16 Xs[16 * 520];
  __shared__ float sred[8][16], sqred[8][16], muL[16], rsL[16];
  const int t = threadIdx.x;
  const int lane = t & 63, w = t >> 6;
  const int g = lane >> 4, li = lane & 15;
  const int i0 = blockIdx.x * 16;
  const int n0 = w * 64;

  #pragma unroll
  for(int it = 0; it < 2; ++it){
    int s = it * 512 + t, row = s >> 6, c8 = s & 63;
    u16x8v xv = *(const u16x8v*)(Xb + (size_t)(i0 + row) * 512 + c8 * 8);
    *(u16x8v*)(Xs + row * 520 + c8 * 8) = xv;
  }
  __syncthreads();

  const u16* wp0 = Wtp + (size_t)(n0 +  0 + li) * 512 + g * 8;
  const u16* wp1 = Wtp + (size_t)(n0 + 16 + li) * 512 + g * 8;
  const u16* wp2 = Wtp + (size_t)(n0 + 32 + li) * 512 + g * 8;
  const u16* wp3 = Wtp + (size_t)(n0 + 48 + li) * 512 + g * 8;

#define LOADW(S, c) { \
  S##0 = *(const s16x8v*)(wp0 + (c) * 32); \
  S##1 = *(const s16x8v*)(wp1 + (c) * 32); \
  S##2 = *(const s16x8v*)(wp2 + (c) * 32); \
  S##3 = *(const s16x8v*)(wp3 + (c) * 32); }
#define COMPW(S, c) { \
  int k0 = (c) * 32 + g * 8; \
  s16x8v a0 = *(const s16x8v*)(Xs + li * 520 + k0); \
  acc[0] = mfma16(a0, S##0, acc[0]); \
  acc[1] = mfma16(a0, S##1, acc[1]); \
  acc[2] = mfma16(a0, S##2, acc[2]); \
  acc[3] = mfma16(a0, S##3, acc[3]); }

  f32x4v acc[4] = {};
  s16x8v wA0, wA1, wA2, wA3, wB0, wB1, wB2, wB3;
  LOADW(wA, 0);
  #pragma unroll
  for(int c = 0; c < 16; c += 2){
    LOADW(wB, c + 1);
    COMPW(wA, c);
    if(c + 2 < 16) LOADW(wA, c + 2);
    COMPW(wB, c + 1);
  }
#undef LOADW
#undef COMPW

  float zres[4][4];
  #pragma unroll
  for(int j = 0; j < 4; ++j){
    int n = n0 + j * 16 + li;
    float bv = bias[n];
    #pragma unroll
    for(int r = 0; r < 4; ++r){
      int i = i0 + g * 4 + r;
      zres[j][r] = acc[j][r] + bv + resid[(size_t)i * 512 + n];
    }
  }
  #pragma unroll
  for(int r = 0; r < 4; ++r){
    float S = 0.f, SQ = 0.f;
    #pragma unroll
    for(int j = 0; j < 4; ++j){ float zz = zres[j][r]; S += zz; SQ += zz * zz; }
    #pragma unroll
    for(int off = 1; off < 16; off <<= 1){ S += __shfl_xor(S, off, 16); SQ += __shfl_xor(SQ, off, 16); }
    if(li == 0){ sred[w][g * 4 + r] = S; sqred[w][g * 4 + r] = SQ; }
  }
  __syncthreads();
  if(t < 16){
    float S = 0.f, SQ = 0.f;
    #pragma unroll
    for(int ww = 0; ww < 8; ++ww){ S += sred[ww][t]; SQ += sqred[ww][t]; }
    float mu = S * (1.0f / 512.0f);
    float var = (SQ - 512.0f * mu * mu) * (1.0f / 511.0f);
    muL[t] = mu;
    rsL[t] = 1.0f / (sqrtf(fmaxf(var, 0.0f)) + 1e-3f);
  }
  __syncthreads();
  #pragma unroll
  for(int r = 0; r < 4; ++r){
    int rloc = g * 4 + r;
    float mu = muL[rloc], rs = rsL[rloc];
    size_t ib = (size_t)(i0 + rloc) * 512;
    #pragma unroll
    for(int j = 0; j < 4; ++j){
      int n = n0 + j * 16 + li;
      Yf[ib + n] = (zres[j][r] - mu) * rs * a2[n] + b2[n];
    }
  }
}

// ---------------------------------------------------------------------------
extern "C" void kernel_launch(void* const* d_in, const int* in_sizes, int n_in,
                              void* d_out, int out_size, void* d_ws, size_t ws_size,
                              hipStream_t stream){
  const float* q      = (const float*)d_in[0];
  const float* k      = (const float*)d_in[1];
  const float* v      = (const float*)d_in[2];
  const float* w_qs   = (const float*)d_in[3];
  const float* w_ks   = (const float*)d_in[4];
  const float* w_vs   = (const float*)d_in[5];
  const float* proj_w = (const float*)d_in[6];
  const float* proj_b = (const float*)d_in[7];
  const float* a2     = (const float*)d_in[8];
  const float* b2     = (const float*)d_in[9];

  char* ws = (char*)d_ws;
  u16* wt    = (u16*)(ws);                       // 3 x 512KB (q-weights pre-scaled)
  u16* wtp   = (u16*)(ws + 1572864);             // 512KB proj_w bf16
  u16* qhh   = (u16*)(ws + 2097152);             // 8 MB head-major
  u16* khh   = (u16*)(ws + 10485760);            // 8 MB head-major
  u16* vtt   = (u16*)(ws + 18874368);            // 8 MB [n][perm(i)]
  u16* xc    = (u16*)(ws + 27262976);            // 8 MB [i][512]

  float* out = (float*)d_out;                    // (4,2048,512) fp32
  float* att = out + 4194304;                    // (32,2048,2048) fp32

  // fold 1/sqrt(512) * log2(e) into the Q projection weights
  const float qscale = 0.06375872032774575f;

  k_wall<<<dim3(1216), 256, 0, stream>>>(w_qs, w_ks, w_vs, proj_w, wt, wtp, qscale);
  k_qkv <<<dim3(256, 6), 256, 0, stream>>>(q, k, v, wt, qhh, khh, vtt);
  k_attn<<<dim3(1024), 256, 0, stream>>>(qhh, khh, vtt, xc, att);
  k_out <<<dim3(512), 512, 0, stream>>>(xc, wtp, out, proj_b, q, a2, b2);
}